// Round 10
// baseline (546.918 us; speedup 1.0000x reference)
//
#include <hip/hip_runtime.h>
#include <math.h>

#define NN 8192
#define DIN 256
#define DOUT 128
#define HS 8208      // hT row stride (bf16 elems), 16416 B (16B-aligned)
#define NSLICE 8     // j-dimension split factor
#define JSL (NN / NSLICE)   // 1024 j per slice

typedef __attribute__((ext_vector_type(8))) short short8;
typedef __attribute__((ext_vector_type(8))) __bf16 bf16x8;
typedef __attribute__((ext_vector_type(4))) float f32x4;
typedef __attribute__((ext_vector_type(4))) unsigned short ushort4v;
typedef __attribute__((ext_vector_type(4))) int int4v;

__device__ __forceinline__ bf16x8 as_bf(short8 s) { return __builtin_bit_cast(bf16x8, s); }
__device__ __forceinline__ unsigned short f2bf(float f) {
  union { float ff; unsigned int i; } v; v.ff = f;
  unsigned int r = v.i + 0x7FFFu + ((v.i >> 16) & 1u);
  return (unsigned short)(r >> 16);
}

// ---- Kernel 0: one-time W -> bf16 conversion + a2key init --------------------
__global__ __launch_bounds__(256) void k0_prep(const float* __restrict__ W,
                                               unsigned short* __restrict__ Wbf,
                                               unsigned int* __restrict__ a2key)
{
  const int i = (blockIdx.x * 256 + threadIdx.x) * 4;   // 32 blocks cover 32768 elems
  f32x4 v = *(const f32x4*)(W + i);
  ushort4v o;
#pragma unroll
  for (int t = 0; t < 4; ++t) o[t] = f2bf(v[t]);
  *(ushort4v*)(Wbf + i) = o;
  if (blockIdx.x == 0 && threadIdx.x == 0) *a2key = 0u;  // keys are always > 0
}

// ---- Kernel 1 (MFMA): hT (bf16, [d][j] padded); a1, a2; global max(a2) ------
__global__ __launch_bounds__(64) void k1_h(
    const float* __restrict__ feat, const unsigned short* __restrict__ Wbf,
    const float* __restrict__ bias, const float* __restrict__ w1,
    const float* __restrict__ b1, const float* __restrict__ w2,
    const float* __restrict__ b2,
    unsigned short* __restrict__ hT,
    float* __restrict__ a1, float* __restrict__ a2,
    unsigned int* __restrict__ a2key)
{
  const int lane = threadIdx.x;
  const int m = lane & 15, q = lane >> 4;
  const int r0 = blockIdx.x * 16;

  f32x4 acc[8] = {};
  const float* fRow = feat + (size_t)(r0 + m) * DIN + q * 8;
#pragma unroll
  for (int k0 = 0; k0 < DIN; k0 += 32) {
    short8 af;
#pragma unroll
    for (int t = 0; t < 8; ++t) af[t] = (short)f2bf(fRow[k0 + t]);
#pragma unroll
    for (int g = 0; g < 8; ++g) {
      const short8 wf = *(const short8*)(Wbf + (size_t)(g * 16 + m) * DIN + k0 + q * 8);
      acc[g] = __builtin_amdgcn_mfma_f32_16x16x32_bf16(as_bf(af), as_bf(wf), acc[g], 0, 0, 0);
    }
  }
  float s1[4] = {0.f, 0.f, 0.f, 0.f}, s2[4] = {0.f, 0.f, 0.f, 0.f};
#pragma unroll
  for (int g = 0; g < 8; ++g) {
    const int d = g * 16 + m;
    const float bv = bias[d];
    const float w1v = w1[d];
    const float w2v = w2[d];
    ushort4v st;
#pragma unroll
    for (int r = 0; r < 4; ++r) {
      float v = acc[g][r] + bv;
      st[r] = f2bf(v);
      s1[r] += v * w1v;
      s2[r] += v * w2v;
    }
    *(ushort4v*)(hT + (size_t)d * HS + r0 + q * 4) = st;  // bf16 hT for k2 B-frags
  }
#pragma unroll
  for (int r = 0; r < 4; ++r) {
    s1[r] += __shfl_xor(s1[r], 1, 64); s2[r] += __shfl_xor(s2[r], 1, 64);
    s1[r] += __shfl_xor(s1[r], 2, 64); s2[r] += __shfl_xor(s2[r], 2, 64);
    s1[r] += __shfl_xor(s1[r], 4, 64); s2[r] += __shfl_xor(s2[r], 4, 64);
    s1[r] += __shfl_xor(s1[r], 8, 64); s2[r] += __shfl_xor(s2[r], 8, 64);
  }
  const float bb1 = b1[0], bb2 = b2[0];
  if (m == 0) {
#pragma unroll
    for (int r = 0; r < 4; ++r) {
      a1[r0 + q * 4 + r] = s1[r] + bb1;
      a2[r0 + q * 4 + r] = s2[r] + bb2;
    }
  }
  float am = fmaxf(fmaxf(s2[0], s2[1]), fmaxf(s2[2], s2[3])) + bb2;
  am = fmaxf(am, __shfl_xor(am, 16, 64));
  am = fmaxf(am, __shfl_xor(am, 32, 64));
  if (lane == 0) {
    unsigned int u = __float_as_uint(am);
    unsigned int key = (u & 0x80000000u) ? ~u : (u | 0x80000000u);  // order-preserving
    atomicMax(a2key, key);
  }
}

// ---- Kernel 2 (MFMA, barrier-free): partial P@H + partial Z per slice --------
// Block = 4 waves x 16 OWN rows (64 rows), each wave does all d=128 (8 C-frags).
// Key identity: lane (m,q)'s A-frag for mfma_16x16x32 is P[row m][k=q*8+t] —
// each thread computes exactly its own fragment's p-values. The P tile never
// leaves registers: NO LDS, NO barriers (Round-6 PMC showed the barriered
// structure latency-bound: VALUBusy 11.5%, hbm 0.3% warm, occ 21.6%).
// Z for row m lives on lanes {m,m+16,m+32,m+48}: 2 shfl_xor -> done.
// Grid 1024 = 4 blocks/CU, all resident; VGPR-only dataflow self-paces.
__global__ __launch_bounds__(256) void GATLayer_46024869544127_kernel(
    const int* __restrict__ adj, const unsigned short* __restrict__ hT,
    const float* __restrict__ a1, const float* __restrict__ a2,
    const unsigned int* __restrict__ a2key,
    float* __restrict__ pacc, float* __restrict__ pz)
{
  const int tid = threadIdx.x;
  const int lane = tid & 63;
  const int w = tid >> 6;                          // wave 0..3
  const int js = blockIdx.x & (NSLICE - 1);
  const int rg = blockIdx.x >> 3;                  // row-group (64 rows)
  const int wr0 = rg * 64 + w * 16;                // this wave's first row
  const int jb = js * JSL;
  const int m = lane & 15, q = lane >> 4;

  const float a1i = a1[wr0 + m];
  const unsigned int kraw = *a2key;
  const unsigned int mu = (kraw & 0x80000000u) ? (kraw ^ 0x80000000u) : ~kraw;
  const float yi = a1i + __uint_as_float(mu);
  const float mi = fmaxf(yi, 0.01f * yi);          // leaky monotonic -> valid shift

  // per-thread streams: row (wr0+m), j = jb + q*8 + [0..7] + 32*ks
  const int* adjT = adj + (size_t)(wr0 + m) * NN + jb + q * 8;
  const float* a2T = a2 + jb + q * 8;
  const unsigned short* hTb = hT + (size_t)m * HS + jb + q * 8;

  f32x4 acc0 = {}, acc1 = {}, acc2 = {}, acc3 = {},
        acc4 = {}, acc5 = {}, acc6 = {}, acc7 = {};
  float zpart = 0.f;

  // 1-kstep-deep prefetch pipeline (named regs only)
  int4v pd0 = *(const int4v*)(adjT);
  int4v pd1 = *(const int4v*)(adjT + 4);
  f32x4 pv0 = *(const f32x4*)(a2T);
  f32x4 pv1 = *(const f32x4*)(a2T + 4);

  const int NKS = JSL / 32;                        // 32 ksteps of K=32
#pragma unroll 4
  for (int ks = 0; ks < NKS; ++ks) {
    const int off = ks * 32;
    // B-frags for this kstep: lane (m,q) = hT[nt*16+m][j off+q*8+t]
    const unsigned short* hb = hTb + off;
    const short8 B0 = *(const short8*)(hb);
    const short8 B1 = *(const short8*)(hb + 16 * HS);
    const short8 B2 = *(const short8*)(hb + 32 * HS);
    const short8 B3 = *(const short8*)(hb + 48 * HS);
    const short8 B4 = *(const short8*)(hb + 64 * HS);
    const short8 B5 = *(const short8*)(hb + 80 * HS);
    const short8 B6 = *(const short8*)(hb + 96 * HS);
    const short8 B7 = *(const short8*)(hb + 112 * HS);

    // exp this kstep's 8 p-values from the pending regs (issued last iter)
    short8 af;
#pragma unroll
    for (int t = 0; t < 4; ++t) {
      float y = a1i + pv0[t];
      float ly = fmaxf(y, 0.01f * y);
      float pv = (pd0[t] > 0) ? __expf(ly - mi) : 0.f;
      zpart += pv;
      af[t] = (short)f2bf(pv);
    }
#pragma unroll
    for (int t = 0; t < 4; ++t) {
      float y = a1i + pv1[t];
      float ly = fmaxf(y, 0.01f * y);
      float pv = (pd1[t] > 0) ? __expf(ly - mi) : 0.f;
      zpart += pv;
      af[4 + t] = (short)f2bf(pv);
    }

    // issue next kstep's adj/a2 (last iter re-reads offset 0: harmless, in-bounds)
    const int noff = (ks + 1 < NKS) ? (off + 32) : 0;
    pd0 = *(const int4v*)(adjT + noff);
    pd1 = *(const int4v*)(adjT + noff + 4);
    pv0 = *(const f32x4*)(a2T + noff);
    pv1 = *(const f32x4*)(a2T + noff + 4);

    // 8 MFMAs: one A-frag x 8 d-tiles
    acc0 = __builtin_amdgcn_mfma_f32_16x16x32_bf16(as_bf(af), as_bf(B0), acc0, 0, 0, 0);
    acc1 = __builtin_amdgcn_mfma_f32_16x16x32_bf16(as_bf(af), as_bf(B1), acc1, 0, 0, 0);
    acc2 = __builtin_amdgcn_mfma_f32_16x16x32_bf16(as_bf(af), as_bf(B2), acc2, 0, 0, 0);
    acc3 = __builtin_amdgcn_mfma_f32_16x16x32_bf16(as_bf(af), as_bf(B3), acc3, 0, 0, 0);
    acc4 = __builtin_amdgcn_mfma_f32_16x16x32_bf16(as_bf(af), as_bf(B4), acc4, 0, 0, 0);
    acc5 = __builtin_amdgcn_mfma_f32_16x16x32_bf16(as_bf(af), as_bf(B5), acc5, 0, 0, 0);
    acc6 = __builtin_amdgcn_mfma_f32_16x16x32_bf16(as_bf(af), as_bf(B6), acc6, 0, 0, 0);
    acc7 = __builtin_amdgcn_mfma_f32_16x16x32_bf16(as_bf(af), as_bf(B7), acc7, 0, 0, 0);
  }

  // Z: row m's partial is spread over lanes {m, m+16, m+32, m+48}
  float zf = zpart;
  zf += __shfl_xor(zf, 16, 64);
  zf += __shfl_xor(zf, 32, 64);
  if (lane < 16) pz[(size_t)js * NN + wr0 + lane] = zf;   // lane==m for q=0

  // D-layout: col = m (d-dim), row = q*4 + r (output row within wave's 16)
  float* po = pacc + (size_t)js * NN * DOUT + (size_t)(wr0 + q * 4) * DOUT + m;
#pragma unroll
  for (int r = 0; r < 4; ++r) {
    float* pr = po + (size_t)r * DOUT;
    pr[0]   = acc0[r]; pr[16]  = acc1[r]; pr[32]  = acc2[r]; pr[48]  = acc3[r];
    pr[64]  = acc4[r]; pr[80]  = acc5[r]; pr[96]  = acc6[r]; pr[112] = acc7[r];
  }
}

// ---- Kernel 3: combine 8 partial slices, normalize by summed Z ---------------
__global__ __launch_bounds__(256) void k3_combine(
    const float* __restrict__ pacc, const float* __restrict__ pz,
    float* __restrict__ out)
{
  const int v = blockIdx.x * 256 + threadIdx.x;   // f32x4 index over NN*DOUT/4
  const int idx = v * 4;
  const int i = idx >> 7;                         // row (DOUT=128)
  const size_t S = (size_t)NN * DOUT;
  f32x4 s = *(const f32x4*)(pacc + idx);
  float Z = pz[i];
#pragma unroll
  for (int sl = 1; sl < NSLICE; ++sl) {
    f32x4 t = *(const f32x4*)(pacc + (size_t)sl * S + idx);
#pragma unroll
    for (int c = 0; c < 4; ++c) s[c] += t[c];
    Z += pz[(size_t)sl * NN + i];
  }
  const float inv = (Z > 0.f) ? 1.f / Z : 0.f;
  f32x4 o;
#pragma unroll
  for (int t = 0; t < 4; ++t) o[t] = s[t] * inv;
  *(f32x4*)(out + idx) = o;
}

extern "C" void kernel_launch(void* const* d_in, const int* in_sizes, int n_in,
                              void* d_out, int out_size, void* d_ws, size_t ws_size,
                              hipStream_t stream) {
  const float* feat = (const float*)d_in[0];
  const int* adj = (const int*)d_in[1];
  const float* W = (const float*)d_in[2];
  const float* b = (const float*)d_in[3];
  const float* w1 = (const float*)d_in[4];
  const float* b1 = (const float*)d_in[5];
  const float* w2 = (const float*)d_in[6];
  const float* b2 = (const float*)d_in[7];
  float* out = (float*)d_out;

  char* ws = (char*)d_ws;
  unsigned short* hT = (unsigned short*)ws;                 // 128*8208*2 B = 2,101,248
  size_t off = (size_t)DOUT * HS * 2;
  float* a1 = (float*)(ws + off);            off += (size_t)NN * 4;
  float* a2 = (float*)(ws + off);            off += (size_t)NN * 4;
  unsigned int* a2key = (unsigned int*)(ws + off); off += 256;     // keep alignment
  unsigned short* Wbf = (unsigned short*)(ws + off); off += (size_t)DOUT * DIN * 2;
  float* pacc = (float*)(ws + off);          off += (size_t)NSLICE * NN * DOUT * 4;
  float* pz   = (float*)(ws + off);          off += (size_t)NSLICE * NN * 4;

  k0_prep<<<DOUT * DIN / (256 * 4), 256, 0, stream>>>(W, Wbf, a2key);
  k1_h<<<512, 64, 0, stream>>>(feat, Wbf, b, w1, b1, w2, b2, hT, a1, a2, a2key);
  GATLayer_46024869544127_kernel<<<(NN / 64) * NSLICE, 256, 0, stream>>>(
      adj, hT, a1, a2, a2key, pacc, pz);
  k3_combine<<<NN * DOUT / (256 * 4), 256, 0, stream>>>(pacc, pz, out);
}

// Round 13
// 427.302 us; speedup vs baseline: 1.2799x; 1.2799x over previous
//
#include <hip/hip_runtime.h>
#include <math.h>

#define NN 8192
#define DIN 256
#define DOUT 128
#define PSTRIDE 136  // p_lds row stride (bf16 elems) = 272 B: 16B-multiple, bank-spread
#define NSLICE 4     // j-dimension split factor
#define JSL (NN / NSLICE)   // 2048 j per slice

// Raw barrier WITHOUT the vmcnt(0) drain __syncthreads() emits (proven correct
// rounds 5-9): only LDS visibility is needed across the tile barrier.
#define BAR_LDS() do { asm volatile("s_waitcnt lgkmcnt(0)" ::: "memory"); \
                       __builtin_amdgcn_s_barrier(); } while (0)

typedef __attribute__((ext_vector_type(8))) short short8;
typedef __attribute__((ext_vector_type(8))) __bf16 bf16x8;
typedef __attribute__((ext_vector_type(4))) float f32x4;
typedef __attribute__((ext_vector_type(4))) unsigned short ushort4v;
typedef __attribute__((ext_vector_type(4))) int int4v;

__device__ __forceinline__ bf16x8 as_bf(short8 s) { return __builtin_bit_cast(bf16x8, s); }
__device__ __forceinline__ unsigned short f2bf(float f) {
  union { float ff; unsigned int i; } v; v.ff = f;
  unsigned int r = v.i + 0x7FFFu + ((v.i >> 16) & 1u);
  return (unsigned short)(r >> 16);
}

// ---- Kernel 0: one-time W -> bf16 conversion + a2key init --------------------
__global__ __launch_bounds__(256) void k0_prep(const float* __restrict__ W,
                                               unsigned short* __restrict__ Wbf,
                                               unsigned int* __restrict__ a2key)
{
  const int i = (blockIdx.x * 256 + threadIdx.x) * 4;   // 32 blocks cover 32768 elems
  f32x4 v = *(const f32x4*)(W + i);
  ushort4v o;
#pragma unroll
  for (int t = 0; t < 4; ++t) o[t] = f2bf(v[t]);
  *(ushort4v*)(Wbf + i) = o;
  if (blockIdx.x == 0 && threadIdx.x == 0) *a2key = 0u;  // keys are always > 0
}

// ---- Kernel 1 (MFMA): packed hTp; a1, a2; global max(a2) --------------------
// hTp layout = MFMA-fragment order: tile (jt32 = j/32, nt = d/16) is 512 bf16
// at (jt32*8 + nt)*512, element (d,j) at lane'*8 + t with
// lane' = (d&15) + ((j>>3)&3)*16, t = j&7. A k2 B-frag load is then ONE
// coalesced 1KB wave-load (16 sequential lines) instead of 16 lines scattered
// across 16KB-strided rows — the round-10-quantified limiter (19K cy/iter
// from ~0.107 lines/cy L2-miss throughput).
__global__ __launch_bounds__(64) void k1_h(
    const float* __restrict__ feat, const unsigned short* __restrict__ Wbf,
    const float* __restrict__ bias, const float* __restrict__ w1,
    const float* __restrict__ b1, const float* __restrict__ w2,
    const float* __restrict__ b2,
    unsigned short* __restrict__ hTp,
    float* __restrict__ a1, float* __restrict__ a2,
    unsigned int* __restrict__ a2key)
{
  const int lane = threadIdx.x;
  const int m = lane & 15, q = lane >> 4;
  const int r0 = blockIdx.x * 16;

  f32x4 acc[8] = {};
  const float* fRow = feat + (size_t)(r0 + m) * DIN + q * 8;
#pragma unroll
  for (int k0 = 0; k0 < DIN; k0 += 32) {
    short8 af;
#pragma unroll
    for (int t = 0; t < 8; ++t) af[t] = (short)f2bf(fRow[k0 + t]);
#pragma unroll
    for (int g = 0; g < 8; ++g) {
      const short8 wf = *(const short8*)(Wbf + (size_t)(g * 16 + m) * DIN + k0 + q * 8);
      acc[g] = __builtin_amdgcn_mfma_f32_16x16x32_bf16(as_bf(af), as_bf(wf), acc[g], 0, 0, 0);
    }
  }
  // packed-store address parts for this thread (j = r0 + q*4 + r, r=0..3):
  // lane' = m + (2*((r0>>4)&1) + (q>>1))*16 ; t = (q&1)*4 + r  (contiguous 4)
  const size_t jt32 = (size_t)(r0 >> 5);
  const int lanep = m + (2 * ((r0 >> 4) & 1) + (q >> 1)) * 16;
  const int tbase = (q & 1) * 4;

  float s1[4] = {0.f, 0.f, 0.f, 0.f}, s2[4] = {0.f, 0.f, 0.f, 0.f};
#pragma unroll
  for (int g = 0; g < 8; ++g) {
    const int d = g * 16 + m;
    const float bv = bias[d];
    const float w1v = w1[d];
    const float w2v = w2[d];
    ushort4v st;
#pragma unroll
    for (int r = 0; r < 4; ++r) {
      float v = acc[g][r] + bv;
      st[r] = f2bf(v);
      s1[r] += v * w1v;
      s2[r] += v * w2v;
    }
    *(ushort4v*)(hTp + (jt32 * 8 + g) * 512 + (size_t)lanep * 8 + tbase) = st;
  }
#pragma unroll
  for (int r = 0; r < 4; ++r) {
    s1[r] += __shfl_xor(s1[r], 1, 64); s2[r] += __shfl_xor(s2[r], 1, 64);
    s1[r] += __shfl_xor(s1[r], 2, 64); s2[r] += __shfl_xor(s2[r], 2, 64);
    s1[r] += __shfl_xor(s1[r], 4, 64); s2[r] += __shfl_xor(s2[r], 4, 64);
    s1[r] += __shfl_xor(s1[r], 8, 64); s2[r] += __shfl_xor(s2[r], 8, 64);
  }
  const float bb1 = b1[0], bb2 = b2[0];
  if (m == 0) {
#pragma unroll
    for (int r = 0; r < 4; ++r) {
      a1[r0 + q * 4 + r] = s1[r] + bb1;
      a2[r0 + q * 4 + r] = s2[r] + bb2;
    }
  }
  float am = fmaxf(fmaxf(s2[0], s2[1]), fmaxf(s2[2], s2[3])) + bb2;
  am = fmaxf(am, __shfl_xor(am, 16, 64));
  am = fmaxf(am, __shfl_xor(am, 32, 64));
  if (lane == 0) {
    unsigned int u = __float_as_uint(am);
    unsigned int key = (u & 0x80000000u) ? ~u : (u | 0x80000000u);  // order-preserving
    atomicMax(a2key, key);
  }
}

// ---- Kernel 2 (MFMA, j-split x4, NT adj, packed-hT): partial P@H + Z ---------
// Round-9 structure (best measured) + two fixes for the quantified L2-miss
// line-throughput limiter: (a) adj loads NON-TEMPORAL so the 256MB stream
// stops evicting the 2MB hTp from each XCD L2; (b) B-frag loads are coalesced
// 1KB wave-loads from the fragment-packed hTp (zero scatter).
__global__ __launch_bounds__(256) void GATLayer_46024869544127_kernel(
    const int* __restrict__ adj, const unsigned short* __restrict__ hTp,
    const float* __restrict__ a1, const float* __restrict__ a2,
    const unsigned int* __restrict__ a2key,
    float* __restrict__ pacc, float* __restrict__ pz)
{
  __shared__ unsigned short p_lds[2][16][PSTRIDE];
  __shared__ float zred[4][16];

  const int tid = threadIdx.x;
  const int lane = tid & 63;
  const int w = tid >> 6;                  // wave 0..3
  const int js = blockIdx.x & (NSLICE - 1);
  const int r0 = (blockIdx.x >> 2) * 16;
  const int jb = js * JSL;
  const int NT = JSL / 128;                // 16 tiles

  // phase-A mapping: thread -> (row, 8-j group)
  const int arow = tid & 15;
  const int ajg = tid >> 4;
  const float a1i = a1[r0 + arow];
  const unsigned int kraw = *a2key;
  const unsigned int mu = (kraw & 0x80000000u) ? (kraw ^ 0x80000000u) : ~kraw;
  const float yi = a1i + __uint_as_float(mu);
  const float mi = fmaxf(yi, 0.01f * yi);  // leaky monotonic -> valid softmax shift

  float zpart = 0.f;
  const int* adjRow = adj + (size_t)(r0 + arow) * NN + jb + ajg * 8;
  const float* a2p = a2 + jb + ajg * 8;

  // phase-B mapping
  const int m = lane & 15, q = lane >> 4;
  const int nt0 = w * 2, nt1 = w * 2 + 1;  // this wave's two d-tiles
  const unsigned short* hTl = hTp + (size_t)lane * 8;

  f32x4 acc0 = {}, acc1 = {};

  // pending regs for the NEXT tile's exp (named scalars -> VGPRs)
  int4v pd0, pd1;
  f32x4 pv0, pv1;

  auto issue = [&](int j0) {
    pd0 = __builtin_nontemporal_load((const int4v*)(adjRow + j0));      // NT: stream
    pd1 = __builtin_nontemporal_load((const int4v*)(adjRow + j0 + 4));  // NT: stream
    pv0 = *(const f32x4*)(a2p + j0);
    pv1 = *(const f32x4*)(a2p + j0 + 4);
  };
  auto expify = [&](ushort4v& o0, ushort4v& o1) {
#pragma unroll
    for (int t = 0; t < 4; ++t) {
      float y = a1i + pv0[t];
      float ly = fmaxf(y, 0.01f * y);
      float pv = (pd0[t] > 0) ? __expf(ly - mi) : 0.f;
      zpart += pv;
      o0[t] = f2bf(pv);
    }
#pragma unroll
    for (int t = 0; t < 4; ++t) {
      float y = a1i + pv1[t];
      float ly = fmaxf(y, 0.01f * y);
      float pv = (pd1[t] > 0) ? __expf(ly - mi) : 0.f;
      zpart += pv;
      o1[t] = f2bf(pv);
    }
  };

  // prologue: tile 0 -> LDS buf0 (synchronous once); issue tile 1 loads
  {
    issue(0);
    ushort4v o0, o1;
    expify(o0, o1);
    *(ushort4v*)&p_lds[0][arow][ajg * 8] = o0;
    *(ushort4v*)&p_lds[0][arow][ajg * 8 + 4] = o1;
  }
  issue(128);
  BAR_LDS();

  for (int jt = 0; jt < NT; ++jt) {
    const int cur = jt & 1;
    const size_t jt32 = (size_t)((jb + jt * 128) >> 5);  // first 32-j tile index
    const bool hasN = (jt + 1) < NT;

    // B-frags for THIS tile: 8 coalesced 1KB wave-loads (no scatter)
    const short8 b00 = *(const short8*)(hTl + ((jt32 + 0) * 8 + nt0) * 512);
    const short8 b01 = *(const short8*)(hTl + ((jt32 + 0) * 8 + nt1) * 512);
    const short8 b10 = *(const short8*)(hTl + ((jt32 + 1) * 8 + nt0) * 512);
    const short8 b11 = *(const short8*)(hTl + ((jt32 + 1) * 8 + nt1) * 512);
    const short8 b20 = *(const short8*)(hTl + ((jt32 + 2) * 8 + nt0) * 512);
    const short8 b21 = *(const short8*)(hTl + ((jt32 + 2) * 8 + nt1) * 512);
    const short8 b30 = *(const short8*)(hTl + ((jt32 + 3) * 8 + nt0) * 512);
    const short8 b31 = *(const short8*)(hTl + ((jt32 + 3) * 8 + nt1) * 512);

    // exp tile jt+1 from pending regs (issued one body ago)
    ushort4v o0, o1;
    if (hasN) expify(o0, o1);

    // issue adj/a2 loads for tile jt+2
    if (jt + 2 < NT) issue((jt + 2) * 128);

    // A-frags from LDS + 8 MFMAs over tile jt
    const short8 af0 = *(const short8*)&p_lds[cur][m][q * 8];
    const short8 af1 = *(const short8*)&p_lds[cur][m][32 + q * 8];
    const short8 af2 = *(const short8*)&p_lds[cur][m][64 + q * 8];
    const short8 af3 = *(const short8*)&p_lds[cur][m][96 + q * 8];
    acc0 = __builtin_amdgcn_mfma_f32_16x16x32_bf16(as_bf(af0), as_bf(b00), acc0, 0, 0, 0);
    acc1 = __builtin_amdgcn_mfma_f32_16x16x32_bf16(as_bf(af0), as_bf(b01), acc1, 0, 0, 0);
    acc0 = __builtin_amdgcn_mfma_f32_16x16x32_bf16(as_bf(af1), as_bf(b10), acc0, 0, 0, 0);
    acc1 = __builtin_amdgcn_mfma_f32_16x16x32_bf16(as_bf(af1), as_bf(b11), acc1, 0, 0, 0);
    acc0 = __builtin_amdgcn_mfma_f32_16x16x32_bf16(as_bf(af2), as_bf(b20), acc0, 0, 0, 0);
    acc1 = __builtin_amdgcn_mfma_f32_16x16x32_bf16(as_bf(af2), as_bf(b21), acc1, 0, 0, 0);
    acc0 = __builtin_amdgcn_mfma_f32_16x16x32_bf16(as_bf(af3), as_bf(b30), acc0, 0, 0, 0);
    acc1 = __builtin_amdgcn_mfma_f32_16x16x32_bf16(as_bf(af3), as_bf(b31), acc1, 0, 0, 0);

    // publish p(jt+1) into the other LDS buffer
    if (hasN) {
      *(ushort4v*)&p_lds[cur ^ 1][arow][ajg * 8] = o0;
      *(ushort4v*)&p_lds[cur ^ 1][arow][ajg * 8 + 4] = o1;
    }
    BAR_LDS();
  }

  // partial-Z reduction for this slice
  float zw = zpart;
  zw += __shfl_xor(zw, 16, 64);
  zw += __shfl_xor(zw, 32, 64);
  if (lane < 16) zred[w][arow] = zw;
  __syncthreads();

  if (tid < 16) {
    __builtin_nontemporal_store(
        zred[0][tid] + zred[1][tid] + zred[2][tid] + zred[3][tid],
        pz + (size_t)js * NN + r0 + tid);
  }
  // D-layout: col=lane&15 (d within tile), row=q*4+r
  const int d0 = w * 32;
#pragma unroll
  for (int r = 0; r < 4; ++r) {
    const int row = q * 4 + r;
    float* po = pacc + (size_t)js * NN * DOUT + (size_t)(r0 + row) * DOUT + d0;
    __builtin_nontemporal_store(acc0[r], po + m);        // NT: don't evict hTp
    __builtin_nontemporal_store(acc1[r], po + 16 + m);
  }
}

// ---- Kernel 3: combine 4 partial slices, normalize by summed Z ---------------
__global__ __launch_bounds__(256) void k3_combine(
    const float* __restrict__ pacc, const float* __restrict__ pz,
    float* __restrict__ out)
{
  const int v = blockIdx.x * 256 + threadIdx.x;   // f32x4 index over NN*DOUT/4
  const int idx = v * 4;
  const int i = idx >> 7;                         // row (DOUT=128)
  const size_t S = (size_t)NN * DOUT;
  f32x4 s0 = __builtin_nontemporal_load((const f32x4*)(pacc + idx));
  f32x4 s1 = __builtin_nontemporal_load((const f32x4*)(pacc + S + idx));
  f32x4 s2 = __builtin_nontemporal_load((const f32x4*)(pacc + 2 * S + idx));
  f32x4 s3 = __builtin_nontemporal_load((const f32x4*)(pacc + 3 * S + idx));
  const float Z = pz[i] + pz[NN + i] + pz[2 * NN + i] + pz[3 * NN + i];
  const float inv = (Z > 0.f) ? 1.f / Z : 0.f;
  f32x4 o;
#pragma unroll
  for (int t = 0; t < 4; ++t) o[t] = (s0[t] + s1[t] + s2[t] + s3[t]) * inv;
  __builtin_nontemporal_store(o, (f32x4*)(out + idx));
}

extern "C" void kernel_launch(void* const* d_in, const int* in_sizes, int n_in,
                              void* d_out, int out_size, void* d_ws, size_t ws_size,
                              hipStream_t stream) {
  const float* feat = (const float*)d_in[0];
  const int* adj = (const int*)d_in[1];
  const float* W = (const float*)d_in[2];
  const float* b = (const float*)d_in[3];
  const float* w1 = (const float*)d_in[4];
  const float* b1 = (const float*)d_in[5];
  const float* w2 = (const float*)d_in[6];
  const float* b2 = (const float*)d_in[7];
  float* out = (float*)d_out;

  char* ws = (char*)d_ws;
  unsigned short* hTp = (unsigned short*)ws;                // 2 MB packed
  size_t off = (size_t)NN * DOUT * 2;
  float* a1 = (float*)(ws + off);            off += (size_t)NN * 4;
  float* a2 = (float*)(ws + off);            off += (size_t)NN * 4;
  unsigned int* a2key = (unsigned int*)(ws + off); off += 256;     // keep alignment
  unsigned short* Wbf = (unsigned short*)(ws + off); off += (size_t)DOUT * DIN * 2;
  float* pacc = (float*)(ws + off);          off += (size_t)NSLICE * NN * DOUT * 4;
  float* pz   = (float*)(ws + off);          off += (size_t)NSLICE * NN * 4;

  k0_prep<<<DOUT * DIN / (256 * 4), 256, 0, stream>>>(W, Wbf, a2key);
  k1_h<<<512, 64, 0, stream>>>(feat, Wbf, b, w1, b1, w2, b2, hTp, a1, a2, a2key);
  GATLayer_46024869544127_kernel<<<(NN / 16) * NSLICE, 256, 0, stream>>>(
      adj, hTp, a1, a2, a2key, pacc, pz);
  k3_combine<<<NN * DOUT / (256 * 4), 256, 0, stream>>>(pacc, pz, out);
}

// Round 14
// 416.435 us; speedup vs baseline: 1.3133x; 1.0261x over previous
//
#include <hip/hip_runtime.h>
#include <math.h>

#define NN 8192
#define DIN 256
#define DOUT 128
#define PSTRIDE 136  // p_lds row stride (bf16 elems) = 272 B: 16B-multiple, bank-spread
#define NSLICE 4     // j-dimension split factor
#define JSL (NN / NSLICE)   // 2048 j per slice

// Raw barrier WITHOUT the vmcnt(0) drain __syncthreads() emits (proven correct
// rounds 5-13): only LDS visibility is needed across the tile barrier.
#define BAR_LDS() do { asm volatile("s_waitcnt lgkmcnt(0)" ::: "memory"); \
                       __builtin_amdgcn_s_barrier(); } while (0)

typedef __attribute__((ext_vector_type(8))) short short8;
typedef __attribute__((ext_vector_type(8))) __bf16 bf16x8;
typedef __attribute__((ext_vector_type(4))) float f32x4;
typedef __attribute__((ext_vector_type(4))) unsigned short ushort4v;
typedef __attribute__((ext_vector_type(4))) int int4v;

__device__ __forceinline__ bf16x8 as_bf(short8 s) { return __builtin_bit_cast(bf16x8, s); }
__device__ __forceinline__ unsigned short f2bf(float f) {
  union { float ff; unsigned int i; } v; v.ff = f;
  unsigned int r = v.i + 0x7FFFu + ((v.i >> 16) & 1u);
  return (unsigned short)(r >> 16);
}

// ---- Kernel 0: one-time W -> bf16 conversion + a2key init --------------------
__global__ __launch_bounds__(256) void k0_prep(const float* __restrict__ W,
                                               unsigned short* __restrict__ Wbf,
                                               unsigned int* __restrict__ a2key)
{
  const int i = (blockIdx.x * 256 + threadIdx.x) * 4;   // 32 blocks cover 32768 elems
  f32x4 v = *(const f32x4*)(W + i);
  ushort4v o;
#pragma unroll
  for (int t = 0; t < 4; ++t) o[t] = f2bf(v[t]);
  *(ushort4v*)(Wbf + i) = o;
  if (blockIdx.x == 0 && threadIdx.x == 0) *a2key = 0u;  // keys are always > 0
}

// ---- Kernel 1 (MFMA): packed hTp; a1, a2; global max(a2) --------------------
// hTp layout = MFMA-fragment order: tile (jt32 = j/32, nt = d/16) is 512 bf16
// at (jt32*8 + nt)*512, element (d,j) at lane'*8 + t with
// lane' = (d&15) + ((j>>3)&3)*16, t = j&7. A k2 B-frag load is then ONE
// coalesced 1KB wave-load (16 sequential lines; L2-friendly).
__global__ __launch_bounds__(64) void k1_h(
    const float* __restrict__ feat, const unsigned short* __restrict__ Wbf,
    const float* __restrict__ bias, const float* __restrict__ w1,
    const float* __restrict__ b1, const float* __restrict__ w2,
    const float* __restrict__ b2,
    unsigned short* __restrict__ hTp,
    float* __restrict__ a1, float* __restrict__ a2,
    unsigned int* __restrict__ a2key)
{
  const int lane = threadIdx.x;
  const int m = lane & 15, q = lane >> 4;
  const int r0 = blockIdx.x * 16;

  f32x4 acc[8] = {};
  const float* fRow = feat + (size_t)(r0 + m) * DIN + q * 8;
#pragma unroll
  for (int k0 = 0; k0 < DIN; k0 += 32) {
    short8 af;
#pragma unroll
    for (int t = 0; t < 8; ++t) af[t] = (short)f2bf(fRow[k0 + t]);
#pragma unroll
    for (int g = 0; g < 8; ++g) {
      const short8 wf = *(const short8*)(Wbf + (size_t)(g * 16 + m) * DIN + k0 + q * 8);
      acc[g] = __builtin_amdgcn_mfma_f32_16x16x32_bf16(as_bf(af), as_bf(wf), acc[g], 0, 0, 0);
    }
  }
  // packed-store address parts for this thread (j = r0 + q*4 + r, r=0..3):
  // lane' = m + (2*((r0>>4)&1) + (q>>1))*16 ; t = (q&1)*4 + r  (contiguous 4)
  const size_t jt32 = (size_t)(r0 >> 5);
  const int lanep = m + (2 * ((r0 >> 4) & 1) + (q >> 1)) * 16;
  const int tbase = (q & 1) * 4;

  float s1[4] = {0.f, 0.f, 0.f, 0.f}, s2[4] = {0.f, 0.f, 0.f, 0.f};
#pragma unroll
  for (int g = 0; g < 8; ++g) {
    const int d = g * 16 + m;
    const float bv = bias[d];
    const float w1v = w1[d];
    const float w2v = w2[d];
    ushort4v st;
#pragma unroll
    for (int r = 0; r < 4; ++r) {
      float v = acc[g][r] + bv;
      st[r] = f2bf(v);
      s1[r] += v * w1v;
      s2[r] += v * w2v;
    }
    *(ushort4v*)(hTp + (jt32 * 8 + g) * 512 + (size_t)lanep * 8 + tbase) = st;
  }
#pragma unroll
  for (int r = 0; r < 4; ++r) {
    s1[r] += __shfl_xor(s1[r], 1, 64); s2[r] += __shfl_xor(s2[r], 1, 64);
    s1[r] += __shfl_xor(s1[r], 2, 64); s2[r] += __shfl_xor(s2[r], 2, 64);
    s1[r] += __shfl_xor(s1[r], 4, 64); s2[r] += __shfl_xor(s2[r], 4, 64);
    s1[r] += __shfl_xor(s1[r], 8, 64); s2[r] += __shfl_xor(s2[r], 8, 64);
  }
  const float bb1 = b1[0], bb2 = b2[0];
  if (m == 0) {
#pragma unroll
    for (int r = 0; r < 4; ++r) {
      a1[r0 + q * 4 + r] = s1[r] + bb1;
      a2[r0 + q * 4 + r] = s2[r] + bb2;
    }
  }
  float am = fmaxf(fmaxf(s2[0], s2[1]), fmaxf(s2[2], s2[3])) + bb2;
  am = fmaxf(am, __shfl_xor(am, 16, 64));
  am = fmaxf(am, __shfl_xor(am, 32, 64));
  if (lane == 0) {
    unsigned int u = __float_as_uint(am);
    unsigned int key = (u & 0x80000000u) ? ~u : (u | 0x80000000u);  // order-preserving
    atomicMax(a2key, key);
  }
}

// ---- Kernel 2 (MFMA, j-split x4, NT adj, packed-hT, coalesced adj) -----------
// Round-13 structure (best measured, 427us e2e) + phase-A mapping TRANSPOSED:
// arow = tid>>4, ajg = tid&15 -> consecutive lanes read consecutive 32B chunks
// of the SAME adj row (512B contiguous runs). adj line-requests per wave-tile
// drop 128 -> 32 and the HBM stream gets burst locality. LDS tile content and
// phase-B are bit-identical (only the writer of each slot changes). Bonus:
// each row's 16 j-groups live in ONE wave -> Z is 4 shuffles + direct store.
__global__ __launch_bounds__(256) void GATLayer_46024869544127_kernel(
    const int* __restrict__ adj, const unsigned short* __restrict__ hTp,
    const float* __restrict__ a1, const float* __restrict__ a2,
    const unsigned int* __restrict__ a2key,
    float* __restrict__ pacc, float* __restrict__ pz)
{
  __shared__ unsigned short p_lds[2][16][PSTRIDE];
  __shared__ float zrow[16];

  const int tid = threadIdx.x;
  const int lane = tid & 63;
  const int w = tid >> 6;                  // wave 0..3
  const int js = blockIdx.x & (NSLICE - 1);
  const int r0 = (blockIdx.x >> 2) * 16;
  const int jb = js * JSL;
  const int NT = JSL / 128;                // 16 tiles

  // phase-A mapping (TRANSPOSED): thread -> (row, 8-j group)
  const int arow = tid >> 4;               // 0..15
  const int ajg = tid & 15;                // 0..15
  const float a1i = a1[r0 + arow];
  const unsigned int kraw = *a2key;
  const unsigned int mu = (kraw & 0x80000000u) ? (kraw ^ 0x80000000u) : ~kraw;
  const float yi = a1i + __uint_as_float(mu);
  const float mi = fmaxf(yi, 0.01f * yi);  // leaky monotonic -> valid softmax shift

  float zpart = 0.f;
  const int* adjRow = adj + (size_t)(r0 + arow) * NN + jb + ajg * 8;
  const float* a2p = a2 + jb + ajg * 8;

  // phase-B mapping
  const int m = lane & 15, q = lane >> 4;
  const int nt0 = w * 2, nt1 = w * 2 + 1;  // this wave's two d-tiles
  const unsigned short* hTl = hTp + (size_t)lane * 8;

  f32x4 acc0 = {}, acc1 = {};

  // pending regs for the NEXT tile's exp (named scalars -> VGPRs)
  int4v pd0, pd1;
  f32x4 pv0, pv1;

  auto issue = [&](int j0) {
    pd0 = __builtin_nontemporal_load((const int4v*)(adjRow + j0));      // NT: stream
    pd1 = __builtin_nontemporal_load((const int4v*)(adjRow + j0 + 4));  // NT: stream
    pv0 = *(const f32x4*)(a2p + j0);
    pv1 = *(const f32x4*)(a2p + j0 + 4);
  };
  auto expify = [&](ushort4v& o0, ushort4v& o1) {
#pragma unroll
    for (int t = 0; t < 4; ++t) {
      float y = a1i + pv0[t];
      float ly = fmaxf(y, 0.01f * y);
      float pv = (pd0[t] > 0) ? __expf(ly - mi) : 0.f;
      zpart += pv;
      o0[t] = f2bf(pv);
    }
#pragma unroll
    for (int t = 0; t < 4; ++t) {
      float y = a1i + pv1[t];
      float ly = fmaxf(y, 0.01f * y);
      float pv = (pd1[t] > 0) ? __expf(ly - mi) : 0.f;
      zpart += pv;
      o1[t] = f2bf(pv);
    }
  };

  // prologue: tile 0 -> LDS buf0 (synchronous once); issue tile 1 loads
  {
    issue(0);
    ushort4v o0, o1;
    expify(o0, o1);
    *(ushort4v*)&p_lds[0][arow][ajg * 8] = o0;
    *(ushort4v*)&p_lds[0][arow][ajg * 8 + 4] = o1;
  }
  issue(128);
  BAR_LDS();

  for (int jt = 0; jt < NT; ++jt) {
    const int cur = jt & 1;
    const size_t jt32 = (size_t)((jb + jt * 128) >> 5);  // first 32-j tile index
    const bool hasN = (jt + 1) < NT;

    // B-frags for THIS tile: 8 coalesced 1KB wave-loads (sequential lines)
    const short8 b00 = *(const short8*)(hTl + ((jt32 + 0) * 8 + nt0) * 512);
    const short8 b01 = *(const short8*)(hTl + ((jt32 + 0) * 8 + nt1) * 512);
    const short8 b10 = *(const short8*)(hTl + ((jt32 + 1) * 8 + nt0) * 512);
    const short8 b11 = *(const short8*)(hTl + ((jt32 + 1) * 8 + nt1) * 512);
    const short8 b20 = *(const short8*)(hTl + ((jt32 + 2) * 8 + nt0) * 512);
    const short8 b21 = *(const short8*)(hTl + ((jt32 + 2) * 8 + nt1) * 512);
    const short8 b30 = *(const short8*)(hTl + ((jt32 + 3) * 8 + nt0) * 512);
    const short8 b31 = *(const short8*)(hTl + ((jt32 + 3) * 8 + nt1) * 512);

    // exp tile jt+1 from pending regs (issued one body ago)
    ushort4v o0, o1;
    if (hasN) expify(o0, o1);

    // issue adj/a2 loads for tile jt+2
    if (jt + 2 < NT) issue((jt + 2) * 128);

    // A-frags from LDS + 8 MFMAs over tile jt
    const short8 af0 = *(const short8*)&p_lds[cur][m][q * 8];
    const short8 af1 = *(const short8*)&p_lds[cur][m][32 + q * 8];
    const short8 af2 = *(const short8*)&p_lds[cur][m][64 + q * 8];
    const short8 af3 = *(const short8*)&p_lds[cur][m][96 + q * 8];
    acc0 = __builtin_amdgcn_mfma_f32_16x16x32_bf16(as_bf(af0), as_bf(b00), acc0, 0, 0, 0);
    acc1 = __builtin_amdgcn_mfma_f32_16x16x32_bf16(as_bf(af0), as_bf(b01), acc1, 0, 0, 0);
    acc0 = __builtin_amdgcn_mfma_f32_16x16x32_bf16(as_bf(af1), as_bf(b10), acc0, 0, 0, 0);
    acc1 = __builtin_amdgcn_mfma_f32_16x16x32_bf16(as_bf(af1), as_bf(b11), acc1, 0, 0, 0);
    acc0 = __builtin_amdgcn_mfma_f32_16x16x32_bf16(as_bf(af2), as_bf(b20), acc0, 0, 0, 0);
    acc1 = __builtin_amdgcn_mfma_f32_16x16x32_bf16(as_bf(af2), as_bf(b21), acc1, 0, 0, 0);
    acc0 = __builtin_amdgcn_mfma_f32_16x16x32_bf16(as_bf(af3), as_bf(b30), acc0, 0, 0, 0);
    acc1 = __builtin_amdgcn_mfma_f32_16x16x32_bf16(as_bf(af3), as_bf(b31), acc1, 0, 0, 0);

    // publish p(jt+1) into the other LDS buffer
    if (hasN) {
      *(ushort4v*)&p_lds[cur ^ 1][arow][ajg * 8] = o0;
      *(ushort4v*)&p_lds[cur ^ 1][arow][ajg * 8 + 4] = o1;
    }
    BAR_LDS();
  }

  // Z: row arow's 16 j-groups are lanes (arow&3)*16 .. +15 of wave (arow>>2)
  float zp = zpart;
  zp += __shfl_xor(zp, 1, 64);
  zp += __shfl_xor(zp, 2, 64);
  zp += __shfl_xor(zp, 4, 64);
  zp += __shfl_xor(zp, 8, 64);
  if ((lane & 15) == 0) zrow[w * 4 + (lane >> 4)] = zp;
  __syncthreads();

  if (tid < 16) {
    __builtin_nontemporal_store(zrow[tid], pz + (size_t)js * NN + r0 + tid);
  }
  // D-layout: col=lane&15 (d within tile), row=q*4+r
  const int d0 = w * 32;
#pragma unroll
  for (int r = 0; r < 4; ++r) {
    const int row = q * 4 + r;
    float* po = pacc + (size_t)js * NN * DOUT + (size_t)(r0 + row) * DOUT + d0;
    __builtin_nontemporal_store(acc0[r], po + m);        // NT: don't evict hTp
    __builtin_nontemporal_store(acc1[r], po + 16 + m);
  }
}

// ---- Kernel 3: combine 4 partial slices, normalize by summed Z ---------------
__global__ __launch_bounds__(256) void k3_combine(
    const float* __restrict__ pacc, const float* __restrict__ pz,
    float* __restrict__ out)
{
  const int v = blockIdx.x * 256 + threadIdx.x;   // f32x4 index over NN*DOUT/4
  const int idx = v * 4;
  const int i = idx >> 7;                         // row (DOUT=128)
  const size_t S = (size_t)NN * DOUT;
  f32x4 s0 = __builtin_nontemporal_load((const f32x4*)(pacc + idx));
  f32x4 s1 = __builtin_nontemporal_load((const f32x4*)(pacc + S + idx));
  f32x4 s2 = __builtin_nontemporal_load((const f32x4*)(pacc + 2 * S + idx));
  f32x4 s3 = __builtin_nontemporal_load((const f32x4*)(pacc + 3 * S + idx));
  const float Z = pz[i] + pz[NN + i] + pz[2 * NN + i] + pz[3 * NN + i];
  const float inv = (Z > 0.f) ? 1.f / Z : 0.f;
  f32x4 o;
#pragma unroll
  for (int t = 0; t < 4; ++t) o[t] = (s0[t] + s1[t] + s2[t] + s3[t]) * inv;
  __builtin_nontemporal_store(o, (f32x4*)(out + idx));
}

extern "C" void kernel_launch(void* const* d_in, const int* in_sizes, int n_in,
                              void* d_out, int out_size, void* d_ws, size_t ws_size,
                              hipStream_t stream) {
  const float* feat = (const float*)d_in[0];
  const int* adj = (const int*)d_in[1];
  const float* W = (const float*)d_in[2];
  const float* b = (const float*)d_in[3];
  const float* w1 = (const float*)d_in[4];
  const float* b1 = (const float*)d_in[5];
  const float* w2 = (const float*)d_in[6];
  const float* b2 = (const float*)d_in[7];
  float* out = (float*)d_out;

  char* ws = (char*)d_ws;
  unsigned short* hTp = (unsigned short*)ws;                // 2 MB packed
  size_t off = (size_t)NN * DOUT * 2;
  float* a1 = (float*)(ws + off);            off += (size_t)NN * 4;
  float* a2 = (float*)(ws + off);            off += (size_t)NN * 4;
  unsigned int* a2key = (unsigned int*)(ws + off); off += 256;     // keep alignment
  unsigned short* Wbf = (unsigned short*)(ws + off); off += (size_t)DOUT * DIN * 2;
  float* pacc = (float*)(ws + off);          off += (size_t)NSLICE * NN * DOUT * 4;
  float* pz   = (float*)(ws + off);          off += (size_t)NSLICE * NN * 4;

  k0_prep<<<DOUT * DIN / (256 * 4), 256, 0, stream>>>(W, Wbf, a2key);
  k1_h<<<512, 64, 0, stream>>>(feat, Wbf, b, w1, b1, w2, b2, hTp, a1, a2, a2key);
  GATLayer_46024869544127_kernel<<<(NN / 16) * NSLICE, 256, 0, stream>>>(
      adj, hTp, a1, a2, a2key, pacc, pz);
  k3_combine<<<NN * DOUT / (256 * 4), 256, 0, stream>>>(pacc, pz, out);
}

// Round 18
// 413.893 us; speedup vs baseline: 1.3214x; 1.0061x over previous
//
#include <hip/hip_runtime.h>
#include <math.h>

#define NN 8192
#define DIN 256
#define DOUT 128
#define PSTRIDE 136  // p_lds row stride (bf16 elems) = 272 B: 16B-multiple, bank-spread
#define NSLICE 8     // j-dimension split factor (chain 8 tiles/block; occ caps at 8 blk/CU)
#define JSL (NN / NSLICE)   // 1024 j per slice

// Raw barrier WITHOUT the vmcnt(0) drain __syncthreads() emits (proven correct
// rounds 5-14): only LDS visibility is needed across the tile barrier.
#define BAR_LDS() do { asm volatile("s_waitcnt lgkmcnt(0)" ::: "memory"); \
                       __builtin_amdgcn_s_barrier(); } while (0)

typedef __attribute__((ext_vector_type(8))) short short8;
typedef __attribute__((ext_vector_type(8))) __bf16 bf16x8;
typedef __attribute__((ext_vector_type(4))) float f32x4;
typedef __attribute__((ext_vector_type(4))) unsigned short ushort4v;
typedef __attribute__((ext_vector_type(4))) int int4v;

__device__ __forceinline__ bf16x8 as_bf(short8 s) { return __builtin_bit_cast(bf16x8, s); }
__device__ __forceinline__ unsigned short f2bf(float f) {
  union { float ff; unsigned int i; } v; v.ff = f;
  unsigned int r = v.i + 0x7FFFu + ((v.i >> 16) & 1u);
  return (unsigned short)(r >> 16);
}

// ---- Kernel 0: one-time W -> bf16 conversion + a2key init --------------------
__global__ __launch_bounds__(256) void k0_prep(const float* __restrict__ W,
                                               unsigned short* __restrict__ Wbf,
                                               unsigned int* __restrict__ a2key)
{
  const int i = (blockIdx.x * 256 + threadIdx.x) * 4;   // 32 blocks cover 32768 elems
  f32x4 v = *(const f32x4*)(W + i);
  ushort4v o;
#pragma unroll
  for (int t = 0; t < 4; ++t) o[t] = f2bf(v[t]);
  *(ushort4v*)(Wbf + i) = o;
  if (blockIdx.x == 0 && threadIdx.x == 0) *a2key = 0u;  // keys are always > 0
}

// ---- Kernel 1 (MFMA): packed hTp; a1, a2; global max(a2) --------------------
// hTp layout = MFMA-fragment order: tile (jt32 = j/32, nt = d/16) is 512 bf16
// at (jt32*8 + nt)*512, element (d,j) at lane'*8 + t with
// lane' = (d&15) + ((j>>3)&3)*16, t = j&7. A k2 B-frag load is then ONE
// coalesced 1KB wave-load (16 sequential lines; L2-friendly).
__global__ __launch_bounds__(64) void k1_h(
    const float* __restrict__ feat, const unsigned short* __restrict__ Wbf,
    const float* __restrict__ bias, const float* __restrict__ w1,
    const float* __restrict__ b1, const float* __restrict__ w2,
    const float* __restrict__ b2,
    unsigned short* __restrict__ hTp,
    float* __restrict__ a1, float* __restrict__ a2,
    unsigned int* __restrict__ a2key)
{
  const int lane = threadIdx.x;
  const int m = lane & 15, q = lane >> 4;
  const int r0 = blockIdx.x * 16;

  f32x4 acc[8] = {};
  const float* fRow = feat + (size_t)(r0 + m) * DIN + q * 8;
#pragma unroll
  for (int k0 = 0; k0 < DIN; k0 += 32) {
    short8 af;
#pragma unroll
    for (int t = 0; t < 8; ++t) af[t] = (short)f2bf(fRow[k0 + t]);
#pragma unroll
    for (int g = 0; g < 8; ++g) {
      const short8 wf = *(const short8*)(Wbf + (size_t)(g * 16 + m) * DIN + k0 + q * 8);
      acc[g] = __builtin_amdgcn_mfma_f32_16x16x32_bf16(as_bf(af), as_bf(wf), acc[g], 0, 0, 0);
    }
  }
  // packed-store address parts for this thread (j = r0 + q*4 + r, r=0..3):
  // lane' = m + (2*((r0>>4)&1) + (q>>1))*16 ; t = (q&1)*4 + r  (contiguous 4)
  const size_t jt32 = (size_t)(r0 >> 5);
  const int lanep = m + (2 * ((r0 >> 4) & 1) + (q >> 1)) * 16;
  const int tbase = (q & 1) * 4;

  float s1[4] = {0.f, 0.f, 0.f, 0.f}, s2[4] = {0.f, 0.f, 0.f, 0.f};
#pragma unroll
  for (int g = 0; g < 8; ++g) {
    const int d = g * 16 + m;
    const float bv = bias[d];
    const float w1v = w1[d];
    const float w2v = w2[d];
    ushort4v st;
#pragma unroll
    for (int r = 0; r < 4; ++r) {
      float v = acc[g][r] + bv;
      st[r] = f2bf(v);
      s1[r] += v * w1v;
      s2[r] += v * w2v;
    }
    *(ushort4v*)(hTp + (jt32 * 8 + g) * 512 + (size_t)lanep * 8 + tbase) = st;
  }
#pragma unroll
  for (int r = 0; r < 4; ++r) {
    s1[r] += __shfl_xor(s1[r], 1, 64); s2[r] += __shfl_xor(s2[r], 1, 64);
    s1[r] += __shfl_xor(s1[r], 2, 64); s2[r] += __shfl_xor(s2[r], 2, 64);
    s1[r] += __shfl_xor(s1[r], 4, 64); s2[r] += __shfl_xor(s2[r], 4, 64);
    s1[r] += __shfl_xor(s1[r], 8, 64); s2[r] += __shfl_xor(s2[r], 8, 64);
  }
  const float bb1 = b1[0], bb2 = b2[0];
  if (m == 0) {
#pragma unroll
    for (int r = 0; r < 4; ++r) {
      a1[r0 + q * 4 + r] = s1[r] + bb1;
      a2[r0 + q * 4 + r] = s2[r] + bb2;
    }
  }
  float am = fmaxf(fmaxf(s2[0], s2[1]), fmaxf(s2[2], s2[3])) + bb2;
  am = fmaxf(am, __shfl_xor(am, 16, 64));
  am = fmaxf(am, __shfl_xor(am, 32, 64));
  if (lane == 0) {
    unsigned int u = __float_as_uint(am);
    unsigned int key = (u & 0x80000000u) ? ~u : (u | 0x80000000u);  // order-preserving
    atomicMax(a2key, key);
  }
}

// ---- Kernel 2 (MFMA, j-split x8, NT adj, packed-hT, coalesced adj) -----------
// Round-14 structure (best measured, 416us e2e) with NSLICE 4->8: per-block
// barrier chain halves to 8 tiles; resident blocks stay at the 8/CU cap
// (LDS 9KB, VGPR 60). Everything else identical to the measured-best kernel.
__global__ __launch_bounds__(256) void GATLayer_46024869544127_kernel(
    const int* __restrict__ adj, const unsigned short* __restrict__ hTp,
    const float* __restrict__ a1, const float* __restrict__ a2,
    const unsigned int* __restrict__ a2key,
    float* __restrict__ pacc, float* __restrict__ pz)
{
  __shared__ unsigned short p_lds[2][16][PSTRIDE];
  __shared__ float zrow[16];

  const int tid = threadIdx.x;
  const int lane = tid & 63;
  const int w = tid >> 6;                  // wave 0..3
  const int js = blockIdx.x & (NSLICE - 1);
  const int r0 = (blockIdx.x >> 3) * 16;
  const int jb = js * JSL;
  const int NT = JSL / 128;                // 8 tiles

  // phase-A mapping (coalesced): thread -> (row, 8-j group)
  const int arow = tid >> 4;               // 0..15
  const int ajg = tid & 15;                // 0..15
  const float a1i = a1[r0 + arow];
  const unsigned int kraw = *a2key;
  const unsigned int mu = (kraw & 0x80000000u) ? (kraw ^ 0x80000000u) : ~kraw;
  const float yi = a1i + __uint_as_float(mu);
  const float mi = fmaxf(yi, 0.01f * yi);  // leaky monotonic -> valid softmax shift

  float zpart = 0.f;
  const int* adjRow = adj + (size_t)(r0 + arow) * NN + jb + ajg * 8;
  const float* a2p = a2 + jb + ajg * 8;

  // phase-B mapping
  const int m = lane & 15, q = lane >> 4;
  const int nt0 = w * 2, nt1 = w * 2 + 1;  // this wave's two d-tiles
  const unsigned short* hTl = hTp + (size_t)lane * 8;

  f32x4 acc0 = {}, acc1 = {};

  // pending regs for the NEXT tile's exp (named scalars -> VGPRs)
  int4v pd0, pd1;
  f32x4 pv0, pv1;

  auto issue = [&](int j0) {
    pd0 = __builtin_nontemporal_load((const int4v*)(adjRow + j0));      // NT: stream
    pd1 = __builtin_nontemporal_load((const int4v*)(adjRow + j0 + 4));  // NT: stream
    pv0 = *(const f32x4*)(a2p + j0);
    pv1 = *(const f32x4*)(a2p + j0 + 4);
  };
  auto expify = [&](ushort4v& o0, ushort4v& o1) {
#pragma unroll
    for (int t = 0; t < 4; ++t) {
      float y = a1i + pv0[t];
      float ly = fmaxf(y, 0.01f * y);
      float pv = (pd0[t] > 0) ? __expf(ly - mi) : 0.f;
      zpart += pv;
      o0[t] = f2bf(pv);
    }
#pragma unroll
    for (int t = 0; t < 4; ++t) {
      float y = a1i + pv1[t];
      float ly = fmaxf(y, 0.01f * y);
      float pv = (pd1[t] > 0) ? __expf(ly - mi) : 0.f;
      zpart += pv;
      o1[t] = f2bf(pv);
    }
  };

  // prologue: tile 0 -> LDS buf0 (synchronous once); issue tile 1 loads
  {
    issue(0);
    ushort4v o0, o1;
    expify(o0, o1);
    *(ushort4v*)&p_lds[0][arow][ajg * 8] = o0;
    *(ushort4v*)&p_lds[0][arow][ajg * 8 + 4] = o1;
  }
  issue(128);
  BAR_LDS();

  for (int jt = 0; jt < NT; ++jt) {
    const int cur = jt & 1;
    const size_t jt32 = (size_t)((jb + jt * 128) >> 5);  // first 32-j tile index
    const bool hasN = (jt + 1) < NT;

    // B-frags for THIS tile: 8 coalesced 1KB wave-loads (sequential lines)
    const short8 b00 = *(const short8*)(hTl + ((jt32 + 0) * 8 + nt0) * 512);
    const short8 b01 = *(const short8*)(hTl + ((jt32 + 0) * 8 + nt1) * 512);
    const short8 b10 = *(const short8*)(hTl + ((jt32 + 1) * 8 + nt0) * 512);
    const short8 b11 = *(const short8*)(hTl + ((jt32 + 1) * 8 + nt1) * 512);
    const short8 b20 = *(const short8*)(hTl + ((jt32 + 2) * 8 + nt0) * 512);
    const short8 b21 = *(const short8*)(hTl + ((jt32 + 2) * 8 + nt1) * 512);
    const short8 b30 = *(const short8*)(hTl + ((jt32 + 3) * 8 + nt0) * 512);
    const short8 b31 = *(const short8*)(hTl + ((jt32 + 3) * 8 + nt1) * 512);

    // exp tile jt+1 from pending regs (issued one body ago)
    ushort4v o0, o1;
    if (hasN) expify(o0, o1);

    // issue adj/a2 loads for tile jt+2
    if (jt + 2 < NT) issue((jt + 2) * 128);

    // A-frags from LDS + 8 MFMAs over tile jt
    const short8 af0 = *(const short8*)&p_lds[cur][m][q * 8];
    const short8 af1 = *(const short8*)&p_lds[cur][m][32 + q * 8];
    const short8 af2 = *(const short8*)&p_lds[cur][m][64 + q * 8];
    const short8 af3 = *(const short8*)&p_lds[cur][m][96 + q * 8];
    acc0 = __builtin_amdgcn_mfma_f32_16x16x32_bf16(as_bf(af0), as_bf(b00), acc0, 0, 0, 0);
    acc1 = __builtin_amdgcn_mfma_f32_16x16x32_bf16(as_bf(af0), as_bf(b01), acc1, 0, 0, 0);
    acc0 = __builtin_amdgcn_mfma_f32_16x16x32_bf16(as_bf(af1), as_bf(b10), acc0, 0, 0, 0);
    acc1 = __builtin_amdgcn_mfma_f32_16x16x32_bf16(as_bf(af1), as_bf(b11), acc1, 0, 0, 0);
    acc0 = __builtin_amdgcn_mfma_f32_16x16x32_bf16(as_bf(af2), as_bf(b20), acc0, 0, 0, 0);
    acc1 = __builtin_amdgcn_mfma_f32_16x16x32_bf16(as_bf(af2), as_bf(b21), acc1, 0, 0, 0);
    acc0 = __builtin_amdgcn_mfma_f32_16x16x32_bf16(as_bf(af3), as_bf(b30), acc0, 0, 0, 0);
    acc1 = __builtin_amdgcn_mfma_f32_16x16x32_bf16(as_bf(af3), as_bf(b31), acc1, 0, 0, 0);

    // publish p(jt+1) into the other LDS buffer
    if (hasN) {
      *(ushort4v*)&p_lds[cur ^ 1][arow][ajg * 8] = o0;
      *(ushort4v*)&p_lds[cur ^ 1][arow][ajg * 8 + 4] = o1;
    }
    BAR_LDS();
  }

  // Z: row arow's 16 j-groups are lanes (arow&3)*16 .. +15 of wave (arow>>2)
  float zp = zpart;
  zp += __shfl_xor(zp, 1, 64);
  zp += __shfl_xor(zp, 2, 64);
  zp += __shfl_xor(zp, 4, 64);
  zp += __shfl_xor(zp, 8, 64);
  if ((lane & 15) == 0) zrow[w * 4 + (lane >> 4)] = zp;
  __syncthreads();

  if (tid < 16) {
    __builtin_nontemporal_store(zrow[tid], pz + (size_t)js * NN + r0 + tid);
  }
  // D-layout: col=lane&15 (d within tile), row=q*4+r
  const int d0 = w * 32;
#pragma unroll
  for (int r = 0; r < 4; ++r) {
    const int row = q * 4 + r;
    float* po = pacc + (size_t)js * NN * DOUT + (size_t)(r0 + row) * DOUT + d0;
    __builtin_nontemporal_store(acc0[r], po + m);        // NT: don't evict hTp
    __builtin_nontemporal_store(acc1[r], po + 16 + m);
  }
}

// ---- Kernel 3: combine 8 partial slices, normalize by summed Z ---------------
__global__ __launch_bounds__(256) void k3_combine(
    const float* __restrict__ pacc, const float* __restrict__ pz,
    float* __restrict__ out)
{
  const int v = blockIdx.x * 256 + threadIdx.x;   // f32x4 index over NN*DOUT/4
  const int idx = v * 4;
  const int i = idx >> 7;                         // row (DOUT=128)
  const size_t S = (size_t)NN * DOUT;
  f32x4 s = __builtin_nontemporal_load((const f32x4*)(pacc + idx));
  float Z = pz[i];
#pragma unroll
  for (int sl = 1; sl < NSLICE; ++sl) {
    f32x4 t = __builtin_nontemporal_load((const f32x4*)(pacc + (size_t)sl * S + idx));
#pragma unroll
    for (int c = 0; c < 4; ++c) s[c] += t[c];
    Z += pz[(size_t)sl * NN + i];
  }
  const float inv = (Z > 0.f) ? 1.f / Z : 0.f;
  f32x4 o;
#pragma unroll
  for (int t = 0; t < 4; ++t) o[t] = s[t] * inv;
  __builtin_nontemporal_store(o, (f32x4*)(out + idx));
}

extern "C" void kernel_launch(void* const* d_in, const int* in_sizes, int n_in,
                              void* d_out, int out_size, void* d_ws, size_t ws_size,
                              hipStream_t stream) {
  const float* feat = (const float*)d_in[0];
  const int* adj = (const int*)d_in[1];
  const float* W = (const float*)d_in[2];
  const float* b = (const float*)d_in[3];
  const float* w1 = (const float*)d_in[4];
  const float* b1 = (const float*)d_in[5];
  const float* w2 = (const float*)d_in[6];
  const float* b2 = (const float*)d_in[7];
  float* out = (float*)d_out;

  char* ws = (char*)d_ws;
  unsigned short* hTp = (unsigned short*)ws;                // 2 MB packed
  size_t off = (size_t)NN * DOUT * 2;
  float* a1 = (float*)(ws + off);            off += (size_t)NN * 4;
  float* a2 = (float*)(ws + off);            off += (size_t)NN * 4;
  unsigned int* a2key = (unsigned int*)(ws + off); off += 256;     // keep alignment
  unsigned short* Wbf = (unsigned short*)(ws + off); off += (size_t)DOUT * DIN * 2;
  float* pacc = (float*)(ws + off);          off += (size_t)NSLICE * NN * DOUT * 4;
  float* pz   = (float*)(ws + off);          off += (size_t)NSLICE * NN * 4;

  k0_prep<<<DOUT * DIN / (256 * 4), 256, 0, stream>>>(W, Wbf, a2key);
  k1_h<<<512, 64, 0, stream>>>(feat, Wbf, b, w1, b1, w2, b2, hTp, a1, a2, a2key);
  GATLayer_46024869544127_kernel<<<(NN / 16) * NSLICE, 256, 0, stream>>>(
      adj, hTp, a1, a2, a2key, pacc, pz);
  k3_combine<<<NN * DOUT / (256 * 4), 256, 0, stream>>>(pacc, pz, out);
}